// Round 4
// baseline (202.402 us; speedup 1.0000x reference)
//
#include <hip/hip_runtime.h>

typedef __bf16 bf16x8 __attribute__((ext_vector_type(8)));
typedef __bf16 bf16x4 __attribute__((ext_vector_type(4)));
typedef short short4v __attribute__((ext_vector_type(4)));
typedef float f32x4 __attribute__((ext_vector_type(4)));

#define LOG2E 1.4426950408889634f

static __device__ __forceinline__ unsigned short f2bf(float f) {
  union { float f; unsigned int u; } c; c.f = f;
  return (unsigned short)((c.u + 0x7fffu + ((c.u >> 16) & 1u)) >> 16);
}

static __device__ __forceinline__ void gload16(const void* g, void* l) {
  __builtin_amdgcn_global_load_lds(
      (const __attribute__((address_space(1))) void*)g,
      (__attribute__((address_space(3))) void*)l, 16, 0, 0);
}

static __device__ __forceinline__ float expfast(float x) {
#if __has_builtin(__builtin_amdgcn_exp2f)
  return __builtin_amdgcn_exp2f(x * LOG2E);
#else
  return exp2f(x * LOG2E);
#endif
}

#if __has_builtin(__builtin_amdgcn_mfma_f32_16x16x16bf16_1k)
#define MFMA16_FALLBACK 0
static __device__ __forceinline__ f32x4 mfma16(bf16x4 a, bf16x4 b, f32x4 c) {
  return __builtin_amdgcn_mfma_f32_16x16x16bf16_1k(
      __builtin_bit_cast(short4v, a), __builtin_bit_cast(short4v, b), c, 0, 0, 0);
}
#else
#define MFMA16_FALLBACK 1
static __device__ __forceinline__ f32x4 mfma16(bf16x4 a, bf16x4 b, f32x4 c) {
  f32x4 d;
  asm("s_nop 1\n\tv_mfma_f32_16x16x16_bf16 %0, %1, %2, %3"
      : "=v"(d) : "v"(a), "v"(b), "v"(c));
  return d;
}
#endif

// ---------------- fused fp32 -> bf16 convert for x + 4 weights ----------------
__global__ void cvt_all(const float* __restrict__ x,
                        const float* __restrict__ Wq,
                        const float* __restrict__ Wk,
                        const float* __restrict__ Wv,
                        const float* __restrict__ Wo,
                        ushort4* __restrict__ dst) {
  int i = blockIdx.x * 256 + threadIdx.x;
  const float* src;
  int off;
  if (i < 1048576) {
    src = x; off = i;
  } else {
    int t = (i - 1048576) >> 18;
    off = (i - 1048576) & 262143;
    src = (t == 0) ? Wq : (t == 1) ? Wk : (t == 2) ? Wv : Wo;
  }
  float4 f = ((const float4*)src)[off];
  ushort4 o;
  o.x = f2bf(f.x); o.y = f2bf(f.y); o.z = f2bf(f.z); o.w = f2bf(f.w);
  dst[i] = o;
}

// ---------------- QKV projection GEMM (unchanged from R3) ----------------
__launch_bounds__(256, 2)
__global__ void qkv_gemm(const unsigned short* __restrict__ xb,
                         const unsigned short* __restrict__ wq,
                         const unsigned short* __restrict__ wk,
                         const unsigned short* __restrict__ wv,
                         const float* __restrict__ bq,
                         const float* __restrict__ bk,
                         const float* __restrict__ bv,
                         unsigned short* __restrict__ Qo,
                         unsigned short* __restrict__ Ko,
                         unsigned short* __restrict__ VTo) {
  __shared__ unsigned short As[128 * 32];
  __shared__ unsigned short Bs[128 * 32];
  const int s0 = blockIdx.x * 128;
  const int n0g = blockIdx.y * 128;
  const int qkv = n0g >> 10;
  const int d0 = n0g & 1023;
  const unsigned short* W = (qkv == 0) ? wq : ((qkv == 1) ? wk : wv);
  const float* bias = (qkv == 0) ? bq : ((qkv == 1) ? bk : bv);

  const unsigned short* Aptr; const unsigned short* Bptr;
  int Aoff, Boff;
  if (qkv < 2) { Aptr = W;  Aoff = d0; Bptr = xb; Boff = s0; }
  else         { Aptr = xb; Aoff = s0; Bptr = W;  Boff = d0; }

  const int tid = threadIdx.x;
  const int lane = tid & 63;
  const int wid = tid >> 6;
  const int wm = (wid >> 1) * 64;
  const int wn = (wid & 1) * 64;
  const int lm = lane & 15;
  const int quad = lane >> 4;

  const int c0 = tid, c1 = 256 + tid;
  const int ar0 = c0 >> 2, aj0 = c0 & 3;
  const int ar1 = c1 >> 2, aj1 = c1 & 3;

  f32x4 acc[4][4] = {};

  for (int kk = 0; kk < 1024; kk += 32) {
    gload16(Aptr + (size_t)(Aoff + ar0) * 1024 + kk + aj0 * 8, As + c0 * 8);
    gload16(Aptr + (size_t)(Aoff + ar1) * 1024 + kk + aj1 * 8, As + c1 * 8);
    gload16(Bptr + (size_t)(Boff + ar0) * 1024 + kk + aj0 * 8, Bs + c0 * 8);
    gload16(Bptr + (size_t)(Boff + ar1) * 1024 + kk + aj1 * 8, Bs + c1 * 8);
    __syncthreads();
    bf16x8 af[4], bff[4];
#pragma unroll
    for (int mt = 0; mt < 4; ++mt)
      af[mt] = *(const bf16x8*)(As + (wm + mt * 16 + lm) * 32 + quad * 8);
#pragma unroll
    for (int nt = 0; nt < 4; ++nt)
      bff[nt] = *(const bf16x8*)(Bs + (wn + nt * 16 + lm) * 32 + quad * 8);
#pragma unroll
    for (int mt = 0; mt < 4; ++mt)
#pragma unroll
      for (int nt = 0; nt < 4; ++nt)
        acc[mt][nt] = __builtin_amdgcn_mfma_f32_16x16x32_bf16(
            af[mt], bff[nt], acc[mt][nt], 0, 0, 0);
    __syncthreads();
  }

  if (qkv < 2) {
    unsigned short* OUT = (qkv == 0) ? Qo : Ko;
    const float scale = (qkv == 0) ? 0.125f : 1.0f;
#pragma unroll
    for (int mt = 0; mt < 4; ++mt) {
      const int d = d0 + wm + mt * 16 + quad * 4;
      const int g = d >> 8, hpg = (d >> 6) & 3, hd = d & 63;
      const float4 bb = *(const float4*)(bias + d);
#pragma unroll
      for (int nt = 0; nt < 4; ++nt) {
        const int srow = s0 + wn + nt * 16 + lm;
        const int bidx = srow >> 11, s = srow & 2047;
        const int head = (bidx * 4 + g) * 4 + hpg;
        ushort4 o;
        o.x = f2bf((acc[mt][nt][0] + bb.x) * scale);
        o.y = f2bf((acc[mt][nt][1] + bb.y) * scale);
        o.z = f2bf((acc[mt][nt][2] + bb.z) * scale);
        o.w = f2bf((acc[mt][nt][3] + bb.w) * scale);
        *(ushort4*)(OUT + (size_t)head * 131072 + (size_t)s * 64 + hd) = o;
      }
    }
  } else {
#pragma unroll
    for (int nt = 0; nt < 4; ++nt) {
      const int d = d0 + wn + nt * 16 + lm;
      const int g = d >> 8, hpg = (d >> 6) & 3, hd = d & 63;
      const float bb = bias[d];
#pragma unroll
      for (int mt = 0; mt < 4; ++mt) {
        const int sbase = s0 + wm + mt * 16 + quad * 4;
        const int bidx = sbase >> 11, s = sbase & 2047;
        const int head = (bidx * 4 + g) * 4 + hpg;
        ushort4 o;
        o.x = f2bf(acc[mt][nt][0] + bb);
        o.y = f2bf(acc[mt][nt][1] + bb);
        o.z = f2bf(acc[mt][nt][2] + bb);
        o.w = f2bf(acc[mt][nt][3] + bb);
        *(ushort4*)(VTo + (size_t)head * 131072 + (size_t)hd * 2048 + s) = o;
      }
    }
  }
}

// ---- K/V staging for 64-kv tiles, 16B-granular XOR swizzle ----
static __device__ __forceinline__ void stage_kv64(
    const unsigned short* Kh, const unsigned short* Vh, int kv0,
    unsigned short* ksl, unsigned short* vsl, int tid) {
#pragma unroll
  for (int t = 0; t < 2; ++t) {
    int i = t * 256 + tid;                 // [0,512)
    int slab = i >> 8, kv = (i >> 2) & 63, tp = i & 3;
    int tc = tp ^ ((kv >> 1) & 3);
    gload16(Kh + (size_t)(kv0 + kv) * 64 + slab * 32 + tc * 8, ksl + (size_t)i * 8);
  }
#pragma unroll
  for (int t = 0; t < 2; ++t) {
    int i = t * 256 + tid;
    int hd = i >> 3, tp = i & 7;
    int tc = tp ^ ((hd >> 1) & 7);
    gload16(Vh + (size_t)hd * 2048 + kv0 + tc * 8, vsl + (size_t)i * 8);
  }
}

// ---------------- attention v3: q-tile 64, kv-tile 64, 4 blocks/CU ----------
// 1024 blocks (32 q-tiles x 32 heads), 32 KB LDS, all blocks co-resident.
// Wave w owns q rows [q0+w*16, +16). S^T = K·Q^T; P^T regs feed V^T·P^T.
__launch_bounds__(256, 4)
__global__ void attn_kernel(const unsigned short* __restrict__ Q,
                            const unsigned short* __restrict__ K,
                            const unsigned short* __restrict__ VT,
                            unsigned short* __restrict__ ctx) {
  __shared__ unsigned short Ks[2][4096];   // [buf][slab2][kv64][32hd]  8KB/buf
  __shared__ unsigned short Vs[2][4096];   // [buf][hd64][kv64]         8KB/buf

  const int head = blockIdx.y;
  const int q0 = blockIdx.x * 64;
  const int b = head >> 4;
  const int colbase = (head & 15) * 64;

  const unsigned short* Kh = K + (size_t)head * 131072;
  const unsigned short* Vh = VT + (size_t)head * 131072;

  const int tid = threadIdx.x;
  const int lane = tid & 63;
  const int w = tid >> 6;
  const int lm = lane & 15;
  const int quad = lane >> 4;

  // Q B-fragments from global (once): qf[c], hd = c*32 + quad*8 + j
  bf16x8 qf[2];
#pragma unroll
  for (int c = 0; c < 2; ++c)
    qf[c] = *(const bf16x8*)(Q + (size_t)head * 131072 +
                             (size_t)(q0 + w * 16 + lm) * 64 + c * 32 + quad * 8);

  stage_kv64(Kh, Vh, 0, Ks[0], Vs[0], tid);
  __syncthreads();

  float psum = 0.f;
  f32x4 oacc[4] = {};
  const int kchunk = (quad ^ ((lm >> 1) & 3)) * 8;

  for (int it = 0; it < 32; ++it) {
    const int buf = it & 1;
    if (it < 31)
      stage_kv64(Kh, Vh, (it + 1) * 64, Ks[buf ^ 1], Vs[buf ^ 1], tid);

    const unsigned short* kb = Ks[buf];
    const unsigned short* vb = Vs[buf];

#pragma unroll
    for (int mt = 0; mt < 4; ++mt) {
      f32x4 s0 = {};
#pragma unroll
      for (int c = 0; c < 2; ++c) {
        bf16x8 kf = *(const bf16x8*)(kb + c * 2048 + (mt * 16 + lm) * 32 + kchunk);
        s0 = __builtin_amdgcn_mfma_f32_16x16x32_bf16(kf, qf[c], s0, 0, 0, 0);
      }
      float e0 = expfast(s0[0]), e1 = expfast(s0[1]);
      float e2 = expfast(s0[2]), e3 = expfast(s0[3]);
      psum += (e0 + e1) + (e2 + e3);
      bf16x4 pf;
      pf[0] = (__bf16)e0; pf[1] = (__bf16)e1; pf[2] = (__bf16)e2; pf[3] = (__bf16)e3;
#pragma unroll
      for (int hm = 0; hm < 4; ++hm) {
        bf16x4 vf = *(const bf16x4*)(vb + (hm * 16 + lm) * 64 +
                                     (((mt * 4 + quad) ^ (lm & 14)) * 4));
        oacc[hm] = mfma16(vf, pf, oacc[hm]);
      }
    }
    __syncthreads();
  }

#if MFMA16_FALLBACK
  asm volatile("s_nop 7\n\ts_nop 7");
#endif
  {
    float p = psum;
    p += __shfl_xor(p, 16, 64);
    p += __shfl_xor(p, 32, 64);
    const float inv = 1.0f / p;
    const size_t row = (size_t)(b * 2048 + q0 + w * 16 + lm);
#pragma unroll
    for (int hm = 0; hm < 4; ++hm) {
      ushort4 o;
      o.x = f2bf(oacc[hm][0] * inv);
      o.y = f2bf(oacc[hm][1] * inv);
      o.z = f2bf(oacc[hm][2] * inv);
      o.w = f2bf(oacc[hm][3] * inv);
      *(ushort4*)(ctx + row * 1024 + colbase + hm * 16 + quad * 4) = o;
    }
  }
}

// ---------------- output projection: tile 128(o) x 64(s), 512 blocks --------
__launch_bounds__(256, 4)
__global__ void out_gemm(const unsigned short* __restrict__ A,   // ctx [4096][1024]
                         const unsigned short* __restrict__ Wb,  // Wo   [1024][1024]
                         const float* __restrict__ bo,
                         float* __restrict__ out) {
  __shared__ unsigned short As[128 * 32];   // Wo rows (o-dim)
  __shared__ unsigned short Bs[64 * 32];    // ctx rows (s-dim)
  const int s0 = blockIdx.x * 64;
  const int o0 = blockIdx.y * 128;

  const int tid = threadIdx.x;
  const int lane = tid & 63;
  const int wid = tid >> 6;
  const int wm = (wid >> 1) * 64;   // o-offset of wave
  const int wn = (wid & 1) * 32;    // s-offset of wave
  const int lm = lane & 15;
  const int quad = lane >> 4;

  const int c0 = tid, c1 = 256 + tid;
  const int ar0 = c0 >> 2, aj0 = c0 & 3;
  const int ar1 = c1 >> 2, aj1 = c1 & 3;

  f32x4 acc[4][2] = {};

  for (int kk = 0; kk < 1024; kk += 32) {
    gload16(Wb + (size_t)(o0 + ar0) * 1024 + kk + aj0 * 8, As + c0 * 8);
    gload16(Wb + (size_t)(o0 + ar1) * 1024 + kk + aj1 * 8, As + c1 * 8);
    gload16(A + (size_t)(s0 + ar0) * 1024 + kk + aj0 * 8, Bs + c0 * 8);
    __syncthreads();
    bf16x8 af[4], bff[2];
#pragma unroll
    for (int mt = 0; mt < 4; ++mt)
      af[mt] = *(const bf16x8*)(As + (wm + mt * 16 + lm) * 32 + quad * 8);
#pragma unroll
    for (int nt = 0; nt < 2; ++nt)
      bff[nt] = *(const bf16x8*)(Bs + (wn + nt * 16 + lm) * 32 + quad * 8);
#pragma unroll
    for (int mt = 0; mt < 4; ++mt)
#pragma unroll
      for (int nt = 0; nt < 2; ++nt)
        acc[mt][nt] = __builtin_amdgcn_mfma_f32_16x16x32_bf16(
            af[mt], bff[nt], acc[mt][nt], 0, 0, 0);
    __syncthreads();
  }

#pragma unroll
  for (int mt = 0; mt < 4; ++mt) {
    const int o = o0 + wm + mt * 16 + quad * 4;
    const float4 bb = *(const float4*)(bo + o);
#pragma unroll
    for (int nt = 0; nt < 2; ++nt) {
      const int s = s0 + wn + nt * 16 + lm;
      float4 v;
      v.x = acc[mt][nt][0] + bb.x;
      v.y = acc[mt][nt][1] + bb.y;
      v.z = acc[mt][nt][2] + bb.z;
      v.w = acc[mt][nt][3] + bb.w;
      *(float4*)(out + (size_t)s * 1024 + o) = v;
    }
  }
}

extern "C" void kernel_launch(void* const* d_in, const int* in_sizes, int n_in,
                              void* d_out, int out_size, void* d_ws, size_t ws_size,
                              hipStream_t stream) {
  const float* x  = (const float*)d_in[0];
  const float* Wq = (const float*)d_in[1];
  const float* bq = (const float*)d_in[2];
  const float* Wk = (const float*)d_in[3];
  const float* bk = (const float*)d_in[4];
  const float* Wv = (const float*)d_in[5];
  const float* bv = (const float*)d_in[6];
  const float* Wo = (const float*)d_in[7];
  const float* bo = (const float*)d_in[8];
  float* out = (float*)d_out;

  char* ws = (char*)d_ws;
  unsigned short* xb  = (unsigned short*)(ws + 0);          //  8 MB
  unsigned short* wqb = (unsigned short*)(ws + 8388608);    //  2 MB
  unsigned short* wkb = (unsigned short*)(ws + 10485760);   //  2 MB
  unsigned short* wvb = (unsigned short*)(ws + 12582912);   //  2 MB
  unsigned short* wob = (unsigned short*)(ws + 14680064);   //  2 MB
  unsigned short* Qb  = (unsigned short*)(ws + 16777216);   //  8 MB [32][2048][64]
  unsigned short* Kb  = (unsigned short*)(ws + 25165824);   //  8 MB [32][2048][64]
  unsigned short* VTb = (unsigned short*)(ws + 33554432);   //  8 MB [32][64][2048]
  unsigned short* ctxb= (unsigned short*)(ws + 41943040);   //  8 MB [4096][1024]
  if (ws_size < 50331648) return;

  cvt_all<<<8192, 256, 0, stream>>>(x, Wq, Wk, Wv, Wo, (ushort4*)ws);
  qkv_gemm<<<dim3(32, 24), 256, 0, stream>>>(xb, wqb, wkb, wvb, bq, bk, bv,
                                             Qb, Kb, VTb);
  attn_kernel<<<dim3(32, 32), 256, 0, stream>>>(Qb, Kb, VTb, ctxb);
  out_gemm<<<dim3(64, 8), 256, 0, stream>>>(ctxb, wob, bo, out);
}

// Round 5
// 197.032 us; speedup vs baseline: 1.0273x; 1.0273x over previous
//
#include <hip/hip_runtime.h>

typedef __bf16 bf16x8 __attribute__((ext_vector_type(8)));
typedef __bf16 bf16x4 __attribute__((ext_vector_type(4)));
typedef short short4v __attribute__((ext_vector_type(4)));
typedef float f32x4 __attribute__((ext_vector_type(4)));

#define LOG2E 1.4426950408889634f

static __device__ __forceinline__ unsigned short f2bf(float f) {
  union { float f; unsigned int u; } c; c.f = f;
  return (unsigned short)((c.u + 0x7fffu + ((c.u >> 16) & 1u)) >> 16);
}

static __device__ __forceinline__ void gload16(const void* g, void* l) {
  __builtin_amdgcn_global_load_lds(
      (const __attribute__((address_space(1))) void*)g,
      (__attribute__((address_space(3))) void*)l, 16, 0, 0);
}

static __device__ __forceinline__ float expfast(float x) {
#if __has_builtin(__builtin_amdgcn_exp2f)
  return __builtin_amdgcn_exp2f(x * LOG2E);
#else
  return exp2f(x * LOG2E);
#endif
}

#if __has_builtin(__builtin_amdgcn_mfma_f32_16x16x16bf16_1k)
#define MFMA16_FALLBACK 0
static __device__ __forceinline__ f32x4 mfma16(bf16x4 a, bf16x4 b, f32x4 c) {
  return __builtin_amdgcn_mfma_f32_16x16x16bf16_1k(
      __builtin_bit_cast(short4v, a), __builtin_bit_cast(short4v, b), c, 0, 0, 0);
}
#else
#define MFMA16_FALLBACK 1
static __device__ __forceinline__ f32x4 mfma16(bf16x4 a, bf16x4 b, f32x4 c) {
  f32x4 d;
  asm("s_nop 1\n\tv_mfma_f32_16x16x16_bf16 %0, %1, %2, %3"
      : "=v"(d) : "v"(a), "v"(b), "v"(c));
  return d;
}
#endif

// ---------------- fused fp32 -> bf16 convert for x + 4 weights ----------------
__global__ void cvt_all(const float* __restrict__ x,
                        const float* __restrict__ Wq,
                        const float* __restrict__ Wk,
                        const float* __restrict__ Wv,
                        const float* __restrict__ Wo,
                        ushort4* __restrict__ dst) {
  int i = blockIdx.x * 256 + threadIdx.x;
  const float* src;
  int off;
  if (i < 1048576) {
    src = x; off = i;
  } else {
    int t = (i - 1048576) >> 18;
    off = (i - 1048576) & 262143;
    src = (t == 0) ? Wq : (t == 1) ? Wk : (t == 2) ? Wv : Wo;
  }
  float4 f = ((const float4*)src)[off];
  ushort4 o;
  o.x = f2bf(f.x); o.y = f2bf(f.y); o.z = f2bf(f.z); o.w = f2bf(f.w);
  dst[i] = o;
}

// ---------------- QKV projection GEMM, BK=64, swizzled LDS ----------------
// Q/K: C^T = W·x^T (d in regs -> ushort4). V: C = x·W^T, written transposed.
__launch_bounds__(256, 2)
__global__ void qkv_gemm(const unsigned short* __restrict__ xb,
                         const unsigned short* __restrict__ wq,
                         const unsigned short* __restrict__ wk,
                         const unsigned short* __restrict__ wv,
                         const float* __restrict__ bq,
                         const float* __restrict__ bk,
                         const float* __restrict__ bv,
                         unsigned short* __restrict__ Qo,
                         unsigned short* __restrict__ Ko,
                         unsigned short* __restrict__ VTo) {
  __shared__ unsigned short As[128 * 64];   // 16 KB
  __shared__ unsigned short Bs[128 * 64];   // 16 KB
  const int s0 = blockIdx.x * 128;
  const int n0g = blockIdx.y * 128;
  const int qkv = n0g >> 10;
  const int d0 = n0g & 1023;
  const unsigned short* W = (qkv == 0) ? wq : ((qkv == 1) ? wk : wv);
  const float* bias = (qkv == 0) ? bq : ((qkv == 1) ? bk : bv);

  const unsigned short* Aptr; const unsigned short* Bptr;
  int Aoff, Boff;
  if (qkv < 2) { Aptr = W;  Aoff = d0; Bptr = xb; Boff = s0; }
  else         { Aptr = xb; Aoff = s0; Bptr = W;  Boff = d0; }

  const int tid = threadIdx.x;
  const int lane = tid & 63;
  const int wid = tid >> 6;
  const int wm = (wid >> 1) * 64;
  const int wn = (wid & 1) * 64;
  const int lm = lane & 15;
  const int quad = lane >> 4;

  f32x4 acc[4][4] = {};

  for (int kk = 0; kk < 1024; kk += 64) {
#pragma unroll
    for (int t = 0; t < 4; ++t) {
      int i = t * 256 + tid;
      int row = i >> 3, tp = i & 7;
      int seg = tp ^ (row & 7);              // global-side swizzle
      gload16(Aptr + (size_t)(Aoff + row) * 1024 + kk + seg * 8,
              As + (size_t)i * 8);
      gload16(Bptr + (size_t)(Boff + row) * 1024 + kk + seg * 8,
              Bs + (size_t)i * 8);
    }
    __syncthreads();
#pragma unroll
    for (int h = 0; h < 2; ++h) {
      bf16x8 af[4], bff[4];
#pragma unroll
      for (int mt = 0; mt < 4; ++mt) {
        int r = wm + mt * 16 + lm;
        af[mt] = *(const bf16x8*)(As + r * 64 + (((h * 4 + quad) ^ (r & 7)) * 8));
      }
#pragma unroll
      for (int nt = 0; nt < 4; ++nt) {
        int r = wn + nt * 16 + lm;
        bff[nt] = *(const bf16x8*)(Bs + r * 64 + (((h * 4 + quad) ^ (r & 7)) * 8));
      }
#pragma unroll
      for (int mt = 0; mt < 4; ++mt)
#pragma unroll
        for (int nt = 0; nt < 4; ++nt)
          acc[mt][nt] = __builtin_amdgcn_mfma_f32_16x16x32_bf16(
              af[mt], bff[nt], acc[mt][nt], 0, 0, 0);
    }
    __syncthreads();
  }

  if (qkv < 2) {
    unsigned short* OUT = (qkv == 0) ? Qo : Ko;
    const float scale = (qkv == 0) ? 0.125f : 1.0f;
#pragma unroll
    for (int mt = 0; mt < 4; ++mt) {
      const int d = d0 + wm + mt * 16 + quad * 4;
      const int g = d >> 8, hpg = (d >> 6) & 3, hd = d & 63;
      const float4 bb = *(const float4*)(bias + d);
#pragma unroll
      for (int nt = 0; nt < 4; ++nt) {
        const int srow = s0 + wn + nt * 16 + lm;
        const int bidx = srow >> 11, s = srow & 2047;
        const int head = (bidx * 4 + g) * 4 + hpg;
        ushort4 o;
        o.x = f2bf((acc[mt][nt][0] + bb.x) * scale);
        o.y = f2bf((acc[mt][nt][1] + bb.y) * scale);
        o.z = f2bf((acc[mt][nt][2] + bb.z) * scale);
        o.w = f2bf((acc[mt][nt][3] + bb.w) * scale);
        *(ushort4*)(OUT + (size_t)head * 131072 + (size_t)s * 64 + hd) = o;
      }
    }
  } else {
#pragma unroll
    for (int nt = 0; nt < 4; ++nt) {
      const int d = d0 + wn + nt * 16 + lm;
      const int g = d >> 8, hpg = (d >> 6) & 3, hd = d & 63;
      const float bb = bias[d];
#pragma unroll
      for (int mt = 0; mt < 4; ++mt) {
        const int sbase = s0 + wm + mt * 16 + quad * 4;
        const int bidx = sbase >> 11, s = sbase & 2047;
        const int head = (bidx * 4 + g) * 4 + hpg;
        ushort4 o;
        o.x = f2bf(acc[mt][nt][0] + bb);
        o.y = f2bf(acc[mt][nt][1] + bb);
        o.z = f2bf(acc[mt][nt][2] + bb);
        o.w = f2bf(acc[mt][nt][3] + bb);
        *(ushort4*)(VTo + (size_t)head * 131072 + (size_t)hd * 2048 + s) = o;
      }
    }
  }
}

// ---- K/V staging (128-kv tiles) with 16B-granular XOR swizzle (R2) ----
static __device__ __forceinline__ void stage_kv(
    const unsigned short* Kh, const unsigned short* Vh, int kv0,
    unsigned short* ksl, unsigned short* vsl, int tid) {
#pragma unroll
  for (int t = 0; t < 4; ++t) {
    int i = t * 256 + tid;
    int slab = i >> 9, kv = (i >> 2) & 127, tp = i & 3;
    int tc = tp ^ ((kv >> 1) & 3);
    gload16(Kh + (size_t)(kv0 + kv) * 64 + slab * 32 + tc * 8, ksl + (size_t)i * 8);
  }
#pragma unroll
  for (int t = 0; t < 4; ++t) {
    int i = t * 256 + tid;
    int hd = i >> 4, tp = i & 15;
    int tc = tp ^ ((hd >> 1) & 7);
    gload16(Vh + (size_t)hd * 2048 + kv0 + tc * 8, vsl + (size_t)i * 8);
  }
}

// ---------------- attention (exact R2 design: q128/kv128, 2 blk/CU) ---------
__launch_bounds__(256, 2)
__global__ void attn_kernel(const unsigned short* __restrict__ Q,
                            const unsigned short* __restrict__ K,
                            const unsigned short* __restrict__ VT,
                            unsigned short* __restrict__ ctx) {
  __shared__ unsigned short Ks[2][8192];
  __shared__ unsigned short Vs[2][8192];

  const int head = blockIdx.y;
  const int q0 = blockIdx.x * 128;
  const int b = head >> 4;
  const int colbase = (head & 15) * 64;

  const unsigned short* Kh = K + (size_t)head * 131072;
  const unsigned short* Vh = VT + (size_t)head * 131072;

  const int tid = threadIdx.x;
  const int lane = tid & 63;
  const int w = tid >> 6;
  const int lm = lane & 15;
  const int quad = lane >> 4;

  bf16x8 qf[2][2];
#pragma unroll
  for (int nt = 0; nt < 2; ++nt) {
    const size_t qrow = (size_t)(q0 + w * 32 + nt * 16 + lm);
#pragma unroll
    for (int c = 0; c < 2; ++c)
      qf[c][nt] = *(const bf16x8*)(Q + (size_t)head * 131072 + qrow * 64 +
                                   c * 32 + quad * 8);
  }

  stage_kv(Kh, Vh, 0, Ks[0], Vs[0], tid);
  __syncthreads();

  float psum[2] = {0.f, 0.f};
  f32x4 oacc[4][2] = {};
  const int kchunk = (quad ^ ((lm >> 1) & 3)) * 8;

  for (int it = 0; it < 16; ++it) {
    const int buf = it & 1;
    if (it < 15)
      stage_kv(Kh, Vh, (it + 1) * 128, Ks[buf ^ 1], Vs[buf ^ 1], tid);

    const unsigned short* kb = Ks[buf];
    const unsigned short* vb = Vs[buf];

#pragma unroll
    for (int mt = 0; mt < 8; ++mt) {
      f32x4 s0 = {}, s1 = {};
#pragma unroll
      for (int c = 0; c < 2; ++c) {
        bf16x8 kf = *(const bf16x8*)(kb + c * 4096 + (mt * 16 + lm) * 32 + kchunk);
        s0 = __builtin_amdgcn_mfma_f32_16x16x32_bf16(kf, qf[c][0], s0, 0, 0, 0);
        s1 = __builtin_amdgcn_mfma_f32_16x16x32_bf16(kf, qf[c][1], s1, 0, 0, 0);
      }
      bf16x4 pf[2];
#pragma unroll
      for (int nt = 0; nt < 2; ++nt) {
        const f32x4 s = nt ? s1 : s0;
        float e0 = expfast(s[0]), e1 = expfast(s[1]);
        float e2 = expfast(s[2]), e3 = expfast(s[3]);
        psum[nt] += (e0 + e1) + (e2 + e3);
        bf16x4 t;
        t[0] = (__bf16)e0; t[1] = (__bf16)e1; t[2] = (__bf16)e2; t[3] = (__bf16)e3;
        pf[nt] = t;
      }
#pragma unroll
      for (int hm = 0; hm < 4; ++hm) {
        bf16x4 vf = *(const bf16x4*)(vb + (hm * 16 + lm) * 128 +
                                     (((mt * 4 + quad) ^ (lm & 14)) * 4));
        oacc[hm][0] = mfma16(vf, pf[0], oacc[hm][0]);
        oacc[hm][1] = mfma16(vf, pf[1], oacc[hm][1]);
      }
    }
    __syncthreads();
  }

#if MFMA16_FALLBACK
  asm volatile("s_nop 7\n\ts_nop 7");
#endif
#pragma unroll
  for (int nt = 0; nt < 2; ++nt) {
    float p = psum[nt];
    p += __shfl_xor(p, 16, 64);
    p += __shfl_xor(p, 32, 64);
    const float inv = 1.0f / p;
    const size_t row = (size_t)(b * 2048 + q0 + w * 32 + nt * 16 + lm);
#pragma unroll
    for (int hm = 0; hm < 4; ++hm) {
      ushort4 o;
      o.x = f2bf(oacc[hm][nt][0] * inv);
      o.y = f2bf(oacc[hm][nt][1] * inv);
      o.z = f2bf(oacc[hm][nt][2] * inv);
      o.w = f2bf(oacc[hm][nt][3] * inv);
      *(ushort4*)(ctx + row * 1024 + colbase + hm * 16 + quad * 4) = o;
    }
  }
}

// -------- output projection: o128 x s64 tile, BK=64, swizzled LDS --------
__launch_bounds__(256, 4)
__global__ void out_gemm(const unsigned short* __restrict__ A,   // ctx [4096][1024]
                         const unsigned short* __restrict__ Wb,  // Wo   [1024][1024]
                         const float* __restrict__ bo,
                         float* __restrict__ out) {
  __shared__ unsigned short As[128 * 64];   // Wo rows (o)   16 KB
  __shared__ unsigned short Bs[64 * 64];    // ctx rows (s)   8 KB
  const int s0 = blockIdx.x * 64;
  const int o0 = blockIdx.y * 128;

  const int tid = threadIdx.x;
  const int lane = tid & 63;
  const int wid = tid >> 6;
  const int wm = (wid >> 1) * 64;   // o
  const int wn = (wid & 1) * 32;    // s
  const int lm = lane & 15;
  const int quad = lane >> 4;

  f32x4 acc[4][2] = {};

  for (int kk = 0; kk < 1024; kk += 64) {
#pragma unroll
    for (int t = 0; t < 4; ++t) {
      int i = t * 256 + tid;
      int row = i >> 3, tp = i & 7;
      int seg = tp ^ (row & 7);
      gload16(Wb + (size_t)(o0 + row) * 1024 + kk + seg * 8, As + (size_t)i * 8);
    }
#pragma unroll
    for (int t = 0; t < 2; ++t) {
      int i = t * 256 + tid;
      int row = i >> 3, tp = i & 7;
      int seg = tp ^ (row & 7);
      gload16(A + (size_t)(s0 + row) * 1024 + kk + seg * 8, Bs + (size_t)i * 8);
    }
    __syncthreads();
#pragma unroll
    for (int h = 0; h < 2; ++h) {
      bf16x8 af[4], bff[2];
#pragma unroll
      for (int mt = 0; mt < 4; ++mt) {
        int r = wm + mt * 16 + lm;
        af[mt] = *(const bf16x8*)(As + r * 64 + (((h * 4 + quad) ^ (r & 7)) * 8));
      }
#pragma unroll
      for (int nt = 0; nt < 2; ++nt) {
        int r = wn + nt * 16 + lm;
        bff[nt] = *(const bf16x8*)(Bs + r * 64 + (((h * 4 + quad) ^ (r & 7)) * 8));
      }
#pragma unroll
      for (int mt = 0; mt < 4; ++mt)
#pragma unroll
        for (int nt = 0; nt < 2; ++nt)
          acc[mt][nt] = __builtin_amdgcn_mfma_f32_16x16x32_bf16(
              af[mt], bff[nt], acc[mt][nt], 0, 0, 0);
    }
    __syncthreads();
  }

#pragma unroll
  for (int mt = 0; mt < 4; ++mt) {
    const int o = o0 + wm + mt * 16 + quad * 4;
    const float4 bb = *(const float4*)(bo + o);
#pragma unroll
    for (int nt = 0; nt < 2; ++nt) {
      const int s = s0 + wn + nt * 16 + lm;
      float4 v;
      v.x = acc[mt][nt][0] + bb.x;
      v.y = acc[mt][nt][1] + bb.y;
      v.z = acc[mt][nt][2] + bb.z;
      v.w = acc[mt][nt][3] + bb.w;
      *(float4*)(out + (size_t)s * 1024 + o) = v;
    }
  }
}

extern "C" void kernel_launch(void* const* d_in, const int* in_sizes, int n_in,
                              void* d_out, int out_size, void* d_ws, size_t ws_size,
                              hipStream_t stream) {
  const float* x  = (const float*)d_in[0];
  const float* Wq = (const float*)d_in[1];
  const float* bq = (const float*)d_in[2];
  const float* Wk = (const float*)d_in[3];
  const float* bk = (const float*)d_in[4];
  const float* Wv = (const float*)d_in[5];
  const float* bv = (const float*)d_in[6];
  const float* Wo = (const float*)d_in[7];
  const float* bo = (const float*)d_in[8];
  float* out = (float*)d_out;

  char* ws = (char*)d_ws;
  unsigned short* xb  = (unsigned short*)(ws + 0);          //  8 MB
  unsigned short* wqb = (unsigned short*)(ws + 8388608);    //  2 MB
  unsigned short* wkb = (unsigned short*)(ws + 10485760);   //  2 MB
  unsigned short* wvb = (unsigned short*)(ws + 12582912);   //  2 MB
  unsigned short* wob = (unsigned short*)(ws + 14680064);   //  2 MB
  unsigned short* Qb  = (unsigned short*)(ws + 16777216);   //  8 MB [32][2048][64]
  unsigned short* Kb  = (unsigned short*)(ws + 25165824);   //  8 MB [32][2048][64]
  unsigned short* VTb = (unsigned short*)(ws + 33554432);   //  8 MB [32][64][2048]
  unsigned short* ctxb= (unsigned short*)(ws + 41943040);   //  8 MB [4096][1024]
  if (ws_size < 50331648) return;

  cvt_all<<<8192, 256, 0, stream>>>(x, Wq, Wk, Wv, Wo, (ushort4*)ws);
  qkv_gemm<<<dim3(32, 24), 256, 0, stream>>>(xb, wqb, wkb, wvb, bq, bk, bv,
                                             Qb, Kb, VTb);
  attn_kernel<<<dim3(16, 32), 256, 0, stream>>>(Qb, Kb, VTb, ctxb);
  out_gemm<<<dim3(64, 8), 256, 0, stream>>>(ctxb, wob, bo, out);
}

// Round 6
// 182.433 us; speedup vs baseline: 1.1095x; 1.0800x over previous
//
#include <hip/hip_runtime.h>

typedef __bf16 bf16x8 __attribute__((ext_vector_type(8)));
typedef __bf16 bf16x4 __attribute__((ext_vector_type(4)));
typedef short short4v __attribute__((ext_vector_type(4)));
typedef float f32x4 __attribute__((ext_vector_type(4)));

#define LOG2E 1.4426950408889634f

static __device__ __forceinline__ unsigned short f2bf(float f) {
  union { float f; unsigned int u; } c; c.f = f;
  return (unsigned short)((c.u + 0x7fffu + ((c.u >> 16) & 1u)) >> 16);
}

static __device__ __forceinline__ void gload16(const void* g, void* l) {
  __builtin_amdgcn_global_load_lds(
      (const __attribute__((address_space(1))) void*)g,
      (__attribute__((address_space(3))) void*)l, 16, 0, 0);
}

// exp2 directly -- LOG2E is pre-folded into Q at the qkv epilogue
static __device__ __forceinline__ float exp2fast(float x) {
#if __has_builtin(__builtin_amdgcn_exp2f)
  return __builtin_amdgcn_exp2f(x);
#else
  return exp2f(x);
#endif
}

#if __has_builtin(__builtin_amdgcn_mfma_f32_16x16x16bf16_1k)
#define MFMA16_FALLBACK 0
static __device__ __forceinline__ f32x4 mfma16(bf16x4 a, bf16x4 b, f32x4 c) {
  return __builtin_amdgcn_mfma_f32_16x16x16bf16_1k(
      __builtin_bit_cast(short4v, a), __builtin_bit_cast(short4v, b), c, 0, 0, 0);
}
#else
#define MFMA16_FALLBACK 1
static __device__ __forceinline__ f32x4 mfma16(bf16x4 a, bf16x4 b, f32x4 c) {
  f32x4 d;
  asm("s_nop 1\n\tv_mfma_f32_16x16x16_bf16 %0, %1, %2, %3"
      : "=v"(d) : "v"(a), "v"(b), "v"(c));
  return d;
}
#endif

// ---------------- fused fp32 -> bf16 convert for x + 4 weights ----------------
__global__ void cvt_all(const float* __restrict__ x,
                        const float* __restrict__ Wq,
                        const float* __restrict__ Wk,
                        const float* __restrict__ Wv,
                        const float* __restrict__ Wo,
                        ushort4* __restrict__ dst) {
  int i = blockIdx.x * 256 + threadIdx.x;
  const float* src;
  int off;
  if (i < 1048576) {
    src = x; off = i;
  } else {
    int t = (i - 1048576) >> 18;
    off = (i - 1048576) & 262143;
    src = (t == 0) ? Wq : (t == 1) ? Wk : (t == 2) ? Wv : Wo;
  }
  float4 f = ((const float4*)src)[off];
  ushort4 o;
  o.x = f2bf(f.x); o.y = f2bf(f.y); o.z = f2bf(f.z); o.w = f2bf(f.w);
  dst[i] = o;
}

// ---------------- QKV projection GEMM, BK=64, swizzled LDS ----------------
__launch_bounds__(256, 2)
__global__ void qkv_gemm(const unsigned short* __restrict__ xb,
                         const unsigned short* __restrict__ wq,
                         const unsigned short* __restrict__ wk,
                         const unsigned short* __restrict__ wv,
                         const float* __restrict__ bq,
                         const float* __restrict__ bk,
                         const float* __restrict__ bv,
                         unsigned short* __restrict__ Qo,
                         unsigned short* __restrict__ Ko,
                         unsigned short* __restrict__ VTo) {
  __shared__ unsigned short As[128 * 64];   // 16 KB
  __shared__ unsigned short Bs[128 * 64];   // 16 KB
  const int s0 = blockIdx.x * 128;
  const int n0g = blockIdx.y * 128;
  const int qkv = n0g >> 10;
  const int d0 = n0g & 1023;
  const unsigned short* W = (qkv == 0) ? wq : ((qkv == 1) ? wk : wv);
  const float* bias = (qkv == 0) ? bq : ((qkv == 1) ? bk : bv);

  const unsigned short* Aptr; const unsigned short* Bptr;
  int Aoff, Boff;
  if (qkv < 2) { Aptr = W;  Aoff = d0; Bptr = xb; Boff = s0; }
  else         { Aptr = xb; Aoff = s0; Bptr = W;  Boff = d0; }

  const int tid = threadIdx.x;
  const int lane = tid & 63;
  const int wid = tid >> 6;
  const int wm = (wid >> 1) * 64;
  const int wn = (wid & 1) * 64;
  const int lm = lane & 15;
  const int quad = lane >> 4;

  f32x4 acc[4][4] = {};

  for (int kk = 0; kk < 1024; kk += 64) {
#pragma unroll
    for (int t = 0; t < 4; ++t) {
      int i = t * 256 + tid;
      int row = i >> 3, tp = i & 7;
      int seg = tp ^ (row & 7);
      gload16(Aptr + (size_t)(Aoff + row) * 1024 + kk + seg * 8,
              As + (size_t)i * 8);
      gload16(Bptr + (size_t)(Boff + row) * 1024 + kk + seg * 8,
              Bs + (size_t)i * 8);
    }
    __syncthreads();
#pragma unroll
    for (int h = 0; h < 2; ++h) {
      bf16x8 af[4], bff[4];
#pragma unroll
      for (int mt = 0; mt < 4; ++mt) {
        int r = wm + mt * 16 + lm;
        af[mt] = *(const bf16x8*)(As + r * 64 + (((h * 4 + quad) ^ (r & 7)) * 8));
      }
#pragma unroll
      for (int nt = 0; nt < 4; ++nt) {
        int r = wn + nt * 16 + lm;
        bff[nt] = *(const bf16x8*)(Bs + r * 64 + (((h * 4 + quad) ^ (r & 7)) * 8));
      }
#pragma unroll
      for (int mt = 0; mt < 4; ++mt)
#pragma unroll
        for (int nt = 0; nt < 4; ++nt)
          acc[mt][nt] = __builtin_amdgcn_mfma_f32_16x16x32_bf16(
              af[mt], bff[nt], acc[mt][nt], 0, 0, 0);
    }
    __syncthreads();
  }

  if (qkv < 2) {
    unsigned short* OUT = (qkv == 0) ? Qo : Ko;
    // Q pre-scale carries SCALE * LOG2E so attention can use exp2 directly
    const float scale = (qkv == 0) ? (0.125f * LOG2E) : 1.0f;
#pragma unroll
    for (int mt = 0; mt < 4; ++mt) {
      const int d = d0 + wm + mt * 16 + quad * 4;
      const int g = d >> 8, hpg = (d >> 6) & 3, hd = d & 63;
      const float4 bb = *(const float4*)(bias + d);
#pragma unroll
      for (int nt = 0; nt < 4; ++nt) {
        const int srow = s0 + wn + nt * 16 + lm;
        const int bidx = srow >> 11, s = srow & 2047;
        const int head = (bidx * 4 + g) * 4 + hpg;
        ushort4 o;
        o.x = f2bf((acc[mt][nt][0] + bb.x) * scale);
        o.y = f2bf((acc[mt][nt][1] + bb.y) * scale);
        o.z = f2bf((acc[mt][nt][2] + bb.z) * scale);
        o.w = f2bf((acc[mt][nt][3] + bb.w) * scale);
        *(ushort4*)(OUT + (size_t)head * 131072 + (size_t)s * 64 + hd) = o;
      }
    }
  } else {
#pragma unroll
    for (int nt = 0; nt < 4; ++nt) {
      const int d = d0 + wn + nt * 16 + lm;
      const int g = d >> 8, hpg = (d >> 6) & 3, hd = d & 63;
      const float bb = bias[d];
#pragma unroll
      for (int mt = 0; mt < 4; ++mt) {
        const int sbase = s0 + wm + mt * 16 + quad * 4;
        const int bidx = sbase >> 11, s = sbase & 2047;
        const int head = (bidx * 4 + g) * 4 + hpg;
        ushort4 o;
        o.x = f2bf(acc[mt][nt][0] + bb);
        o.y = f2bf(acc[mt][nt][1] + bb);
        o.z = f2bf(acc[mt][nt][2] + bb);
        o.w = f2bf(acc[mt][nt][3] + bb);
        *(ushort4*)(VTo + (size_t)head * 131072 + (size_t)hd * 2048 + s) = o;
      }
    }
  }
}

// ---- K/V staging (128-kv tiles) with 16B-granular XOR swizzle ----
static __device__ __forceinline__ void stage_kv(
    const unsigned short* Kh, const unsigned short* Vh, int kv0,
    unsigned short* ksl, unsigned short* vsl, int tid) {
#pragma unroll
  for (int t = 0; t < 4; ++t) {
    int i = t * 256 + tid;
    int slab = i >> 9, kv = (i >> 2) & 127, tp = i & 3;
    int tc = tp ^ ((kv >> 1) & 3);
    gload16(Kh + (size_t)(kv0 + kv) * 64 + slab * 32 + tc * 8, ksl + (size_t)i * 8);
  }
#pragma unroll
  for (int t = 0; t < 4; ++t) {
    int i = t * 256 + tid;
    int hd = i >> 4, tp = i & 15;
    int tc = tp ^ ((hd >> 1) & 7);
    gload16(Vh + (size_t)hd * 2048 + kv0 + tc * 8, vsl + (size_t)i * 8);
  }
}

// ------ attention v4: q128/kv128 tile, waves split 2x2 over (kv x q) --------
// Wave w: wq = w&1 (q rows [q0+wq*64, +64) as 4 n-tiles), wkv = w>>1
// (kv stripe [wkv*64, +64) within each 128-kv tile). Fragment reuse per LDS
// read doubles vs R2 (4 nt), halving LDS-read traffic. Cross-wave O/psum
// reduction over wkv through LDS (overlaid on dead K buffers) at the end.
__launch_bounds__(256, 2)
__global__ void attn_kernel(const unsigned short* __restrict__ Q,
                            const unsigned short* __restrict__ K,
                            const unsigned short* __restrict__ VT,
                            unsigned short* __restrict__ ctx) {
  __shared__ __align__(16) unsigned char smem[65536];
  // carve: Ks[buf] at 0/16384, Vs[buf] at 32768/49152 (16 KB each)
  // reduction overlay: red (128 rows x 68 floats) at 0, psred at 34816

  const int head = blockIdx.y;
  const int q0 = blockIdx.x * 128;
  const int b = head >> 4;
  const int colbase = (head & 15) * 64;

  const unsigned short* Kh = K + (size_t)head * 131072;
  const unsigned short* Vh = VT + (size_t)head * 131072;

  const int tid = threadIdx.x;
  const int lane = tid & 63;
  const int w = tid >> 6;
  const int wq = w & 1;
  const int wkv = w >> 1;
  const int lm = lane & 15;
  const int quad = lane >> 4;

  // Q B-fragments: q row = q0 + wq*64 + nt*16 + lm, hd = c*32 + quad*8 + j
  bf16x8 qf[2][4];
#pragma unroll
  for (int nt = 0; nt < 4; ++nt) {
    const size_t qrow = (size_t)(q0 + wq * 64 + nt * 16 + lm);
#pragma unroll
    for (int c = 0; c < 2; ++c)
      qf[c][nt] = *(const bf16x8*)(Q + (size_t)head * 131072 + qrow * 64 +
                                   c * 32 + quad * 8);
  }

  stage_kv(Kh, Vh, 0, (unsigned short*)smem,
           (unsigned short*)(smem + 32768), tid);
  __syncthreads();

  float psum[4] = {0.f, 0.f, 0.f, 0.f};
  f32x4 oacc[4][4] = {};   // [hm][nt]
  const int kchunk = (quad ^ ((lm >> 1) & 3)) * 8;

  for (int it = 0; it < 16; ++it) {
    const int buf = it & 1;
    const unsigned short* kb = (const unsigned short*)(smem + buf * 16384);
    const unsigned short* vb = (const unsigned short*)(smem + 32768 + buf * 16384);
    if (it < 15)
      stage_kv(Kh, Vh, (it + 1) * 128,
               (unsigned short*)(smem + (buf ^ 1) * 16384),
               (unsigned short*)(smem + 32768 + (buf ^ 1) * 16384), tid);

#pragma unroll
    for (int mt = 0; mt < 4; ++mt) {
      const int kvrow = wkv * 64 + mt * 16 + lm;
      f32x4 s[4] = {};
#pragma unroll
      for (int c = 0; c < 2; ++c) {
        bf16x8 kf = *(const bf16x8*)(kb + c * 4096 + kvrow * 32 + kchunk);
#pragma unroll
        for (int nt = 0; nt < 4; ++nt)
          s[nt] = __builtin_amdgcn_mfma_f32_16x16x32_bf16(kf, qf[c][nt], s[nt],
                                                          0, 0, 0);
      }
      bf16x4 pf[4];
#pragma unroll
      for (int nt = 0; nt < 4; ++nt) {
        float e0 = exp2fast(s[nt][0]), e1 = exp2fast(s[nt][1]);
        float e2 = exp2fast(s[nt][2]), e3 = exp2fast(s[nt][3]);
        psum[nt] += (e0 + e1) + (e2 + e3);
        bf16x4 t;
        t[0] = (__bf16)e0; t[1] = (__bf16)e1; t[2] = (__bf16)e2; t[3] = (__bf16)e3;
        pf[nt] = t;
      }
      const int vgran = ((wkv * 16 + mt * 4 + quad) ^ (lm & 14)) * 4;
#pragma unroll
      for (int hm = 0; hm < 4; ++hm) {
        bf16x4 vf = *(const bf16x4*)(vb + (hm * 16 + lm) * 128 + vgran);
#pragma unroll
        for (int nt = 0; nt < 4; ++nt)
          oacc[hm][nt] = mfma16(vf, pf[nt], oacc[hm][nt]);
      }
    }
    __syncthreads();
  }

#if MFMA16_FALLBACK
  asm volatile("s_nop 7\n\ts_nop 7");
#endif
  // quad-reduce psum (sums the kv-subchunks held across quads)
#pragma unroll
  for (int nt = 0; nt < 4; ++nt) {
    psum[nt] += __shfl_xor(psum[nt], 16, 64);
    psum[nt] += __shfl_xor(psum[nt], 32, 64);
  }

  float* red = (float*)smem;               // 128 x 68 floats = 34816 B
  float* psred = (float*)(smem + 34816);   // 128 floats
  if (wkv == 1) {
#pragma unroll
    for (int nt = 0; nt < 4; ++nt) {
      const int qi = wq * 64 + nt * 16 + lm;
      if (quad == 0) psred[qi] = psum[nt];
#pragma unroll
      for (int hm = 0; hm < 4; ++hm)
        *(f32x4*)(red + qi * 68 + hm * 16 + quad * 4) = oacc[hm][nt];
    }
  }
  __syncthreads();
  if (wkv == 0) {
#pragma unroll
    for (int nt = 0; nt < 4; ++nt) {
      const int qi = wq * 64 + nt * 16 + lm;
      const float inv = 1.0f / (psum[nt] + psred[qi]);
      const size_t row = (size_t)(b * 2048 + q0 + qi);
#pragma unroll
      for (int hm = 0; hm < 4; ++hm) {
        f32x4 o = *(const f32x4*)(red + qi * 68 + hm * 16 + quad * 4);
        o += oacc[hm][nt];
        ushort4 st;
        st.x = f2bf(o[0] * inv);
        st.y = f2bf(o[1] * inv);
        st.z = f2bf(o[2] * inv);
        st.w = f2bf(o[3] * inv);
        *(ushort4*)(ctx + row * 1024 + colbase + hm * 16 + quad * 4) = st;
      }
    }
  }
}

// -------- output projection: o128 x s64 tile, BK=64, swizzled LDS --------
__launch_bounds__(256, 4)
__global__ void out_gemm(const unsigned short* __restrict__ A,   // ctx [4096][1024]
                         const unsigned short* __restrict__ Wb,  // Wo   [1024][1024]
                         const float* __restrict__ bo,
                         float* __restrict__ out) {
  __shared__ unsigned short As[128 * 64];   // Wo rows (o)   16 KB
  __shared__ unsigned short Bs[64 * 64];    // ctx rows (s)   8 KB
  const int s0 = blockIdx.x * 64;
  const int o0 = blockIdx.y * 128;

  const int tid = threadIdx.x;
  const int lane = tid & 63;
  const int wid = tid >> 6;
  const int wm = (wid >> 1) * 64;   // o
  const int wn = (wid & 1) * 32;    // s
  const int lm = lane & 15;
  const int quad = lane >> 4;

  f32x4 acc[4][2] = {};

  for (int kk = 0; kk < 1024; kk += 64) {
#pragma unroll
    for (int t = 0; t < 4; ++t) {
      int i = t * 256 + tid;
      int row = i >> 3, tp = i & 7;
      int seg = tp ^ (row & 7);
      gload16(Wb + (size_t)(o0 + row) * 1024 + kk + seg * 8, As + (size_t)i * 8);
    }
#pragma unroll
    for (int t = 0; t < 2; ++t) {
      int i = t * 256 + tid;
      int row = i >> 3, tp = i & 7;
      int seg = tp ^ (row & 7);
      gload16(A + (size_t)(s0 + row) * 1024 + kk + seg * 8, Bs + (size_t)i * 8);
    }
    __syncthreads();
#pragma unroll
    for (int h = 0; h < 2; ++h) {
      bf16x8 af[4], bff[2];
#pragma unroll
      for (int mt = 0; mt < 4; ++mt) {
        int r = wm + mt * 16 + lm;
        af[mt] = *(const bf16x8*)(As + r * 64 + (((h * 4 + quad) ^ (r & 7)) * 8));
      }
#pragma unroll
      for (int nt = 0; nt < 2; ++nt) {
        int r = wn + nt * 16 + lm;
        bff[nt] = *(const bf16x8*)(Bs + r * 64 + (((h * 4 + quad) ^ (r & 7)) * 8));
      }
#pragma unroll
      for (int mt = 0; mt < 4; ++mt)
#pragma unroll
        for (int nt = 0; nt < 2; ++nt)
          acc[mt][nt] = __builtin_amdgcn_mfma_f32_16x16x32_bf16(
              af[mt], bff[nt], acc[mt][nt], 0, 0, 0);
    }
    __syncthreads();
  }

#pragma unroll
  for (int mt = 0; mt < 4; ++mt) {
    const int o = o0 + wm + mt * 16 + quad * 4;
    const float4 bb = *(const float4*)(bo + o);
#pragma unroll
    for (int nt = 0; nt < 2; ++nt) {
      const int s = s0 + wn + nt * 16 + lm;
      float4 v;
      v.x = acc[mt][nt][0] + bb.x;
      v.y = acc[mt][nt][1] + bb.y;
      v.z = acc[mt][nt][2] + bb.z;
      v.w = acc[mt][nt][3] + bb.w;
      *(float4*)(out + (size_t)s * 1024 + o) = v;
    }
  }
}

extern "C" void kernel_launch(void* const* d_in, const int* in_sizes, int n_in,
                              void* d_out, int out_size, void* d_ws, size_t ws_size,
                              hipStream_t stream) {
  const float* x  = (const float*)d_in[0];
  const float* Wq = (const float*)d_in[1];
  const float* bq = (const float*)d_in[2];
  const float* Wk = (const float*)d_in[3];
  const float* bk = (const float*)d_in[4];
  const float* Wv = (const float*)d_in[5];
  const float* bv = (const float*)d_in[6];
  const float* Wo = (const float*)d_in[7];
  const float* bo = (const float*)d_in[8];
  float* out = (float*)d_out;

  char* ws = (char*)d_ws;
  unsigned short* xb  = (unsigned short*)(ws + 0);          //  8 MB
  unsigned short* wqb = (unsigned short*)(ws + 8388608);    //  2 MB
  unsigned short* wkb = (unsigned short*)(ws + 10485760);   //  2 MB
  unsigned short* wvb = (unsigned short*)(ws + 12582912);   //  2 MB
  unsigned short* wob = (unsigned short*)(ws + 14680064);   //  2 MB
  unsigned short* Qb  = (unsigned short*)(ws + 16777216);   //  8 MB [32][2048][64]
  unsigned short* Kb  = (unsigned short*)(ws + 25165824);   //  8 MB [32][2048][64]
  unsigned short* VTb = (unsigned short*)(ws + 33554432);   //  8 MB [32][64][2048]
  unsigned short* ctxb= (unsigned short*)(ws + 41943040);   //  8 MB [4096][1024]
  if (ws_size < 50331648) return;

  cvt_all<<<8192, 256, 0, stream>>>(x, Wq, Wk, Wv, Wo, (ushort4*)ws);
  qkv_gemm<<<dim3(32, 24), 256, 0, stream>>>(xb, wqb, wkb, wvb, bq, bk, bv,
                                             Qb, Kb, VTb);
  attn_kernel<<<dim3(16, 32), 256, 0, stream>>>(Qb, Kb, VTb, ctxb);
  out_gemm<<<dim3(64, 8), 256, 0, stream>>>(ctxb, wob, bo, out);
}